// Round 7
// baseline (497.251 us; speedup 1.0000x reference)
//
#include <hip/hip_runtime.h>
#include <hip/hip_bf16.h>

// TalkingHeads: BS=2, C_IN=512, SEQ=1024, DK=DV=64, H=16. fp32 I/O.
// Round 7: J^T dataflow. jc = mfma(K,Q) puts (k=quad*4+r, q=l15, all h) in
// registers -> Wl mix, exp, invl, Ww mix all in-register (weights via
// wave-uniform scalar loads). U lands directly in PV A-frag position; only the
// v-index crosses waves, via a lane-indexed padded LDS exchange (conflict-free).
// No J transpose LDS, 2 barriers/round, LDS ~36KB.

#define B_S  2
#define C_INN 512
#define SEQL 1024
#define D_K  64
#define N_H  16
#define BQJ  (2 * 1024 * 1024)   // elements of one O partial [b][q][j]
#define KSL  16                  // lpart grid split (x4 waves -> 64 chunks)
#define KSO  8                   // opart split

typedef __attribute__((ext_vector_type(4))) float floatx4;
typedef __attribute__((ext_vector_type(8))) short short8;
typedef __attribute__((ext_vector_type(2))) unsigned int uint2v;

static __device__ __forceinline__ float bf2f(unsigned short u) {
  union { unsigned int i; float f; } x; x.i = ((unsigned int)u) << 16; return x.f;
}
static __device__ __forceinline__ unsigned short f2bf(float f) {
  union { float f; unsigned int i; } x; x.f = f;
  return (unsigned short)((x.i + 0x7fffu + ((x.i >> 16) & 1u)) >> 16);
}
static __device__ __forceinline__ unsigned int pkbf(float a, float b) {
  return (unsigned int)f2bf(a) | ((unsigned int)f2bf(b) << 16);
}

// ---------------------------------------------------------------------------
// Kernel 1: QKV projection (fp32 in, bf16 out).
// Q,K -> [b][h][s][d] ; V -> [b][v][d][s].
// ---------------------------------------------------------------------------
__global__ __launch_bounds__(256) void ath_qkv(
    const float* __restrict__ inp,
    const float* __restrict__ Wq,
    const float* __restrict__ Wk,
    const float* __restrict__ Wv,
    const float* __restrict__ Aq,
    const float* __restrict__ Ak,
    const float* __restrict__ Av,
    unsigned short* __restrict__ ws)
{
  const int sblk = blockIdx.x;
  const int nblk = blockIdx.y;
  const int z = blockIdx.z;
  const int b = z / 3, p = z % 3;
  const float* W  = (p == 0) ? Wq : ((p == 1) ? Wk : Wv);
  const float* Ap = (p == 0) ? Aq : ((p == 1) ? Ak : Av);
  const float sig = 1.0f / (1.0f + __expf(-Ap[0]));

  __shared__ __align__(16) unsigned short As[64][40];
  __shared__ __align__(16) unsigned short Bs[64][40];

  const int tid = threadIdx.x;
  const int w = tid >> 6, lane = tid & 63;
  const int l15 = lane & 15, quad = lane >> 4;

  floatx4 acc[4];
#pragma unroll
  for (int i = 0; i < 4; ++i) acc[i] = (floatx4){0.f, 0.f, 0.f, 0.f};

  for (int cc = 0; cc < 16; ++cc) {
    const int c0 = cc * 32;
    __syncthreads();
#pragma unroll
    for (int t = 0; t < 2; ++t) {
      const int i = tid * 2 + t;
      const int c = i >> 4, sq = i & 15;
      const floatx4 g = *(const floatx4*)(inp + ((size_t)(b * C_INN + c0 + c) * SEQL + sblk * 64 + sq * 4));
      As[sq * 4 + 0][c] = f2bf(g[0]); As[sq * 4 + 1][c] = f2bf(g[1]);
      As[sq * 4 + 2][c] = f2bf(g[2]); As[sq * 4 + 3][c] = f2bf(g[3]);
    }
#pragma unroll
    for (int t = 0; t < 2; ++t) {
      const int i = tid * 2 + t;
      const int c = i >> 4, nq = i & 15;
      const floatx4 g = *(const floatx4*)(W + ((size_t)(c0 + c) * 1024 + nblk * 64 + nq * 4));
      Bs[nq * 4 + 0][c] = f2bf(g[0]); Bs[nq * 4 + 1][c] = f2bf(g[1]);
      Bs[nq * 4 + 2][c] = f2bf(g[2]); Bs[nq * 4 + 3][c] = f2bf(g[3]);
    }
    __syncthreads();
    const short8 a = *(const short8*)&As[w * 16 + l15][quad * 8];
#pragma unroll
    for (int nt = 0; nt < 4; ++nt) {
      const short8 bb = *(const short8*)&Bs[nt * 16 + l15][quad * 8];
      acc[nt] = __builtin_amdgcn_mfma_f32_16x16x32_bf16(a, bb, acc[nt], 0, 0, 0);
    }
  }

  unsigned short* out = ws + (size_t)p * ((size_t)B_S * N_H * SEQL * D_K);
#pragma unroll
  for (int nt = 0; nt < 4; ++nt) {
    const int h = l15;
    const int d = nblk * 4 + nt;
#pragma unroll
    for (int r = 0; r < 4; ++r) {
      const int s = sblk * 64 + w * 16 + quad * 4 + r;
      const float vout = acc[nt][r] * sig;
      if (p == 2) out[((size_t)((b * N_H + h) * D_K + d)) * SEQL + s] = f2bf(vout);
      else        out[((size_t)((b * N_H + h) * SEQL + s)) * D_K + d] = f2bf(vout);
    }
  }
}

// ---------------------------------------------------------------------------
// K2a: partial l. grid(64 qblk, KSL, 2 b); wave w handles 16-k tile ks*64+w*16
// independently (kse = ks*4+w, 64 chunks). J^T in registers, no LDS.
// ---------------------------------------------------------------------------
__global__ __launch_bounds__(256, 4) void ath_lpart(
    const float* __restrict__ maskp,
    const float* __restrict__ Wl,
    const unsigned short* __restrict__ qkv,
    float* __restrict__ lp)
{
  const int qblk = blockIdx.x;
  const int ks   = blockIdx.y;
  const int b    = blockIdx.z;
  const int tid = threadIdx.x;
  const int w = tid >> 6, lane = tid & 63;
  const int l15 = lane & 15, quad = lane >> 4;

  const unsigned short* Qf = qkv;
  const unsigned short* Kf = qkv + (size_t)B_S * N_H * SEQL * D_K;

  const int kabs0 = ks * 64 + w * 16;

  // J^T: jc[h] holds J[k=quad*4+r][q=l15] in regs 0..3
  floatx4 jc[16];
#pragma unroll
  for (int h = 0; h < 16; ++h) {
    const unsigned short* qb = Qf + ((size_t)((b * N_H + h) * SEQL) + qblk * 16 + l15) * D_K;
    const unsigned short* kb = Kf + ((size_t)((b * N_H + h) * SEQL) + kabs0 + l15) * D_K;
    const short8 q0 = *(const short8*)(qb + quad * 8);
    const short8 q1 = *(const short8*)(qb + 32 + quad * 8);
    const short8 k0 = *(const short8*)(kb + quad * 8);
    const short8 k1 = *(const short8*)(kb + 32 + quad * 8);
    floatx4 c = (floatx4){0.f, 0.f, 0.f, 0.f};
    c = __builtin_amdgcn_mfma_f32_16x16x32_bf16(k0, q0, c, 0, 0, 0);  // A=K -> rows k
    c = __builtin_amdgcn_mfma_f32_16x16x32_bf16(k1, q1, c, 0, 0, 0);
    jc[h] = c;
  }

  float mk[4];
#pragma unroll
  for (int r = 0; r < 4; ++r) mk[r] = maskp[b * SEQL + kabs0 + quad * 4 + r];

  float lac[16];
#pragma unroll
  for (int g = 0; g < 16; ++g) {
    float e0 = -mk[0], e1 = -mk[1], e2 = -mk[2], e3 = -mk[3];
#pragma unroll
    for (int h = 0; h < 16; ++h) {
      const float wv = Wl[h * 16 + g];  // wave-uniform -> scalar load
      e0 += jc[h][0] * wv; e1 += jc[h][1] * wv;
      e2 += jc[h][2] * wv; e3 += jc[h][3] * wv;
    }
    lac[g] = __expf(fminf(fmaxf(e0, -60.f), 60.f)) + __expf(fminf(fmaxf(e1, -60.f), 60.f))
           + __expf(fminf(fmaxf(e2, -60.f), 60.f)) + __expf(fminf(fmaxf(e3, -60.f), 60.f));
  }

  // reduce across the 4 quads (same l15)
#pragma unroll
  for (int g = 0; g < 16; ++g) {
    float v = lac[g];
    v += __shfl_xor(v, 16);
    v += __shfl_xor(v, 32);
    lac[g] = v;
  }
  if (quad == 0) {
    const int kse = ks * 4 + w;
    float* dst = lp + ((size_t)((kse * 2 + b) * SEQL + qblk * 16 + l15)) * 16;
#pragma unroll
    for (int g4 = 0; g4 < 4; ++g4)
      *(floatx4*)(dst + g4 * 4) = (floatx4){lac[g4 * 4], lac[g4 * 4 + 1], lac[g4 * 4 + 2], lac[g4 * 4 + 3]};
  }
}

// ---------------------------------------------------------------------------
// K2r: invl = 1 / sum_{kse<64} lp. grid(128, 256 thr).
// ---------------------------------------------------------------------------
__global__ __launch_bounds__(256) void ath_linv(
    const float* __restrict__ lp, float* __restrict__ invl)
{
  const int t = blockIdx.x * 256 + threadIdx.x;
  const int b = t >> 14, rem = t & 16383;
  float s = 0.f;
  for (int kse = 0; kse < 64; ++kse) s += lp[(size_t)((kse * 2 + b)) * 16384 + rem];
  invl[t] = 1.0f / fmaxf(s, 1e-37f);
}

// ---------------------------------------------------------------------------
// K2b: partial O. grid(64 qblk, KSO, 2 b). kchunk=128 -> 2 rounds of 64 k
// (wave w owns 16-k tile w). Per round: J^T+mix+U in registers, U -> LDS
// v-exchange (lane-indexed, padded), barrier, V-phase (bf16 K=32 MFMA), barrier.
// ---------------------------------------------------------------------------
__global__ __launch_bounds__(256, 2) void ath_opart(
    const float* __restrict__ maskp,
    const float* __restrict__ Wl,
    const float* __restrict__ Ww,
    const unsigned short* __restrict__ qkv,
    const float* __restrict__ invl,
    unsigned short* __restrict__ Obp)
{
  const int qblk = blockIdx.x;
  const int ks   = blockIdx.y;
  const int b    = blockIdx.z;
  const int tid = threadIdx.x;
  const int w = tid >> 6, lane = tid & 63;
  const int l15 = lane & 15, quad = lane >> 4;

  const unsigned short* Qf = qkv;
  const unsigned short* Kf = qkv + (size_t)B_S * N_H * SEQL * D_K;
  const unsigned short* Vf = qkv + 2 * (size_t)B_S * N_H * SEQL * D_K;

  // Us: b64 slots [tile4][v16][qw4][q16 +1pad] -> 4*16*4*17 slots * 8B = 34.8KB
  __shared__ __align__(16) unsigned int UsU[4 * 16 * 4 * 17 * 2];
  __shared__ float invls[16][16];
  uint2v* Us2 = (uint2v*)UsU;

  invls[tid >> 4][tid & 15] =
      invl[(size_t)b * 16384 + (qblk * 16 + (tid >> 4)) * 16 + (tid & 15)];

  floatx4 oacc[4][4];
#pragma unroll
  for (int a = 0; a < 4; ++a)
#pragma unroll
    for (int d = 0; d < 4; ++d) oacc[a][d] = (floatx4){0.f, 0.f, 0.f, 0.f};

  __syncthreads();  // invls visible

  for (int rd = 0; rd < 2; ++rd) {
    const int kabs0 = ks * 128 + rd * 64 + w * 16;

    // ---- J^T for all 16 heads (registers) ----
    floatx4 jc[16];
#pragma unroll
    for (int h = 0; h < 16; ++h) {
      const unsigned short* qb = Qf + ((size_t)((b * N_H + h) * SEQL) + qblk * 16 + l15) * D_K;
      const unsigned short* kb = Kf + ((size_t)((b * N_H + h) * SEQL) + kabs0 + l15) * D_K;
      const short8 q0 = *(const short8*)(qb + quad * 8);
      const short8 q1 = *(const short8*)(qb + 32 + quad * 8);
      const short8 k0 = *(const short8*)(kb + quad * 8);
      const short8 k1 = *(const short8*)(kb + 32 + quad * 8);
      floatx4 c = (floatx4){0.f, 0.f, 0.f, 0.f};
      c = __builtin_amdgcn_mfma_f32_16x16x32_bf16(k0, q0, c, 0, 0, 0);
      c = __builtin_amdgcn_mfma_f32_16x16x32_bf16(k1, q1, c, 0, 0, 0);
      jc[h] = c;
    }

    float mk[4];
#pragma unroll
    for (int r = 0; r < 4; ++r) mk[r] = maskp[b * SEQL + kabs0 + quad * 4 + r];

    // ---- EL mix + softmax -> p[r][g] (registers; Wl scalar-uniform) ----
    float p[4][16];
#pragma unroll
    for (int g = 0; g < 16; ++g) {
      float e0 = -mk[0], e1 = -mk[1], e2 = -mk[2], e3 = -mk[3];
#pragma unroll
      for (int h = 0; h < 16; ++h) {
        const float wv = Wl[h * 16 + g];
        e0 += jc[h][0] * wv; e1 += jc[h][1] * wv;
        e2 += jc[h][2] * wv; e3 += jc[h][3] * wv;
      }
      const float iv = invls[l15][g];
      p[0][g] = __expf(fminf(fmaxf(e0, -60.f), 60.f)) * iv;
      p[1][g] = __expf(fminf(fmaxf(e1, -60.f), 60.f)) * iv;
      p[2][g] = __expf(fminf(fmaxf(e2, -60.f), 60.f)) * iv;
      p[3][g] = __expf(fminf(fmaxf(e3, -60.f), 60.f)) * iv;
    }

    // ---- U mix (registers; Ww scalar-uniform) -> Us exchange ----
#pragma unroll
    for (int v = 0; v < 16; ++v) {
      float u0 = 0.f, u1 = 0.f, u2 = 0.f, u3 = 0.f;
#pragma unroll
      for (int g = 0; g < 16; ++g) {
        const float wv = Ww[g * 16 + v];
        u0 += p[0][g] * wv; u1 += p[1][g] * wv;
        u2 += p[2][g] * wv; u3 += p[3][g] * wv;
      }
      Us2[((w * 16 + v) * 4 + quad) * 17 + l15] = (uint2v){pkbf(u0, u1), pkbf(u2, u3)};
    }

    __syncthreads();  // all waves' U ready

    // ---- V-phase: wave w -> v = 4w..4w+3, two K=32 MFMAs cover 64 k ----
#pragma unroll
    for (int tp = 0; tp < 2; ++tp) {
      const int t = tp * 2 + (quad >> 1);
      const int qwb = (quad & 1) * 2;
      const int kt_abs = ks * 128 + rd * 64 + tp * 32;
#pragma unroll
      for (int vv = 0; vv < 4; ++vv) {
        const int v = w * 4 + vv;
        const int i1 = ((t * 16 + v) * 4 + qwb) * 17 + l15;
        union { uint2v a[2]; short8 s; } ux;
        ux.a[0] = Us2[i1];
        ux.a[1] = Us2[i1 + 17];
#pragma unroll
        for (int dt = 0; dt < 4; ++dt) {
          const short8 vfr = *(const short8*)(Vf +
              ((size_t)((b * N_H + v) * D_K + dt * 16 + l15)) * SEQL + kt_abs + quad * 8);
          oacc[vv][dt] = __builtin_amdgcn_mfma_f32_16x16x32_bf16(ux.s, vfr, oacc[vv][dt], 0, 0, 0);
        }
      }
    }

    __syncthreads();  // Us free for next round
  }

  // write partial O bf16: Obp[ks][b][q][d*16+v]
#pragma unroll
  for (int vv = 0; vv < 4; ++vv) {
    const int v = w * 4 + vv;
#pragma unroll
    for (int dt = 0; dt < 4; ++dt) {
      const int d = dt * 16 + l15;
#pragma unroll
      for (int r = 0; r < 4; ++r) {
        const int q = qblk * 16 + quad * 4 + r;
        Obp[(size_t)ks * BQJ + ((size_t)(b * SEQL + q)) * 1024 + d * 16 + v] = f2bf(oacc[vv][dt][r]);
      }
    }
  }
}

// ---------------------------------------------------------------------------
// K2s: Obsum = sum_ks Obp. grid(1024, 256 thr).
// ---------------------------------------------------------------------------
__global__ __launch_bounds__(256) void ath_osum(
    const unsigned short* __restrict__ Obp,
    unsigned short* __restrict__ Obsum)
{
  const size_t i = ((size_t)blockIdx.x * 256 + threadIdx.x) * 8;
  float a[8];
#pragma unroll
  for (int e = 0; e < 8; ++e) a[e] = 0.f;
#pragma unroll
  for (int ks = 0; ks < KSO; ++ks) {
    const short8 v = *(const short8*)(Obp + (size_t)ks * BQJ + i);
#pragma unroll
    for (int e = 0; e < 8; ++e) a[e] += bf2f((unsigned short)v[e]);
  }
  short8 o;
#pragma unroll
  for (int e = 0; e < 8; ++e) o[e] = (short)f2bf(a[e]);
  *(short8*)(Obsum + i) = o;
}

// ---------------------------------------------------------------------------
// Kernel 3: out[b][co][q] = inp + sum_j Obsum[b][q][j] * Wo[j][co]. fp32 out.
// ---------------------------------------------------------------------------
__global__ __launch_bounds__(256) void ath_out(
    const float* __restrict__ inp,
    const float* __restrict__ Wo,
    const unsigned short* __restrict__ Ob,
    float* __restrict__ out)
{
  const int qblk = blockIdx.x;
  const int cblk = blockIdx.y;
  const int b    = blockIdx.z;
  const int tid = threadIdx.x;
  const int w = tid >> 6, lane = tid & 63;
  const int l15 = lane & 15, quad = lane >> 4;

  __shared__ __align__(16) unsigned short Os[64][40];
  __shared__ __align__(16) unsigned short Wt[64][40];

  floatx4 acc[4];
#pragma unroll
  for (int i = 0; i < 4; ++i) acc[i] = (floatx4){0.f, 0.f, 0.f, 0.f};

  for (int jc = 0; jc < 32; ++jc) {
    const int j0 = jc * 32;
    __syncthreads();
    {
      const int q = tid >> 2, jq = tid & 3;
      const unsigned short* g = Ob + ((size_t)(b * SEQL + qblk * 64 + q)) * 1024 + j0 + jq * 8;
      *(short8*)&Os[q][jq * 8] = *(const short8*)g;
    }
#pragma unroll
    for (int t = 0; t < 2; ++t) {
      const int i = tid * 2 + t;
      const int j = i >> 4, cq = i & 15;
      const floatx4 g = *(const floatx4*)(Wo + ((size_t)(j0 + j) * 512 + cblk * 64 + cq * 4));
      Wt[cq * 4 + 0][j] = f2bf(g[0]); Wt[cq * 4 + 1][j] = f2bf(g[1]);
      Wt[cq * 4 + 2][j] = f2bf(g[2]); Wt[cq * 4 + 3][j] = f2bf(g[3]);
    }
    __syncthreads();
    const short8 a = *(const short8*)&Os[w * 16 + l15][quad * 8];
#pragma unroll
    for (int nt = 0; nt < 4; ++nt) {
      const short8 bb = *(const short8*)&Wt[nt * 16 + l15][quad * 8];
      acc[nt] = __builtin_amdgcn_mfma_f32_16x16x32_bf16(a, bb, acc[nt], 0, 0, 0);
    }
  }

#pragma unroll
  for (int nt = 0; nt < 4; ++nt) {
    const int co = cblk * 64 + nt * 16 + l15;
    const int qb = qblk * 64 + w * 16 + quad * 4;
    const float* ip = inp + ((size_t)(b * 512 + co)) * SEQL + qb;
    float* op = out + ((size_t)(b * 512 + co)) * SEQL + qb;
#pragma unroll
    for (int r = 0; r < 4; ++r) op[r] = acc[nt][r] + ip[r];
  }
}

// ---------------------------------------------------------------------------
extern "C" void kernel_launch(void* const* d_in, const int* in_sizes, int n_in,
                              void* d_out, int out_size, void* d_ws, size_t ws_size,
                              hipStream_t stream) {
  (void)in_sizes; (void)n_in; (void)out_size; (void)ws_size;
  const float* inp   = (const float*)d_in[0];
  const float* maskp = (const float*)d_in[1];
  const float* Wq    = (const float*)d_in[2];
  const float* Wk    = (const float*)d_in[3];
  const float* Wv    = (const float*)d_in[4];
  const float* Aq    = (const float*)d_in[5];
  const float* Ak    = (const float*)d_in[6];
  const float* Av    = (const float*)d_in[7];
  const float* Wl    = (const float*)d_in[8];
  const float* Ww    = (const float*)d_in[9];
  const float* Wo    = (const float*)d_in[10];

  const size_t MB = 1u << 20;
  unsigned short* qkv   = (unsigned short*)d_ws;                       // 12 MB bf16 Q,K,V
  unsigned short* Obsum = (unsigned short*)((char*)d_ws + 12 * MB);    // 4 MB bf16
  float*          invl  = (float*)((char*)d_ws + 16 * MB);             // 128 KB
  float*          lp    = (float*)((char*)d_ws + 18 * MB);             // 8 MB (dead before Obp use)
  unsigned short* Obp   = (unsigned short*)((char*)d_ws + 18 * MB);    // KSO*4 MB = 32 MB
  float* out = (float*)d_out;

  ath_qkv<<<dim3(16, 16, 6), 256, 0, stream>>>(inp, Wq, Wk, Wv, Aq, Ak, Av, qkv);
  ath_lpart<<<dim3(64, KSL, 2), 256, 0, stream>>>(maskp, Wl, qkv, lp);
  ath_linv<<<dim3(128), 256, 0, stream>>>(lp, invl);
  ath_opart<<<dim3(64, KSO, 2), 256, 0, stream>>>(maskp, Wl, Ww, qkv, invl, Obp);
  ath_osum<<<dim3(1024), 256, 0, stream>>>(Obp, Obsum);
  ath_out<<<dim3(16, 8, 2), 256, 0, stream>>>(inp, Wo, Obsum, out);
}

// Round 8
// 490.725 us; speedup vs baseline: 1.0133x; 1.0133x over previous
//
#include <hip/hip_runtime.h>
#include <hip/hip_bf16.h>

// TalkingHeads: BS=2, C_IN=512, SEQ=1024, DK=DV=64, H=16. fp32 I/O.
// Round 8: r7 J^T register dataflow, spill-fixed. Heads processed in 2 groups
// of 8: jc8[8] (32 regs) folded immediately into persistent el[16] (64 regs);
// exp/invl in-place; Ww mix reads el. Peak VGPR ~110 (+AGPR oacc) -> no
// scratch. Us exchange (aligned, conflict-light) unchanged from r7.

#define B_S  2
#define C_INN 512
#define SEQL 1024
#define D_K  64
#define N_H  16
#define BQJ  (2 * 1024 * 1024)   // elements of one O partial [b][q][j]
#define KSL  16                  // lpart grid split (x4 waves -> 64 chunks)
#define KSO  8                   // opart split

typedef __attribute__((ext_vector_type(4))) float floatx4;
typedef __attribute__((ext_vector_type(8))) short short8;
typedef __attribute__((ext_vector_type(2))) unsigned int uint2v;

static __device__ __forceinline__ float bf2f(unsigned short u) {
  union { unsigned int i; float f; } x; x.i = ((unsigned int)u) << 16; return x.f;
}
static __device__ __forceinline__ unsigned short f2bf(float f) {
  union { float f; unsigned int i; } x; x.f = f;
  return (unsigned short)((x.i + 0x7fffu + ((x.i >> 16) & 1u)) >> 16);
}
static __device__ __forceinline__ unsigned int pkbf(float a, float b) {
  return (unsigned int)f2bf(a) | ((unsigned int)f2bf(b) << 16);
}

// ---------------------------------------------------------------------------
// Kernel 1: QKV projection (fp32 in, bf16 out).
// Q,K -> [b][h][s][d] ; V -> [b][v][d][s].
// ---------------------------------------------------------------------------
__global__ __launch_bounds__(256) void ath_qkv(
    const float* __restrict__ inp,
    const float* __restrict__ Wq,
    const float* __restrict__ Wk,
    const float* __restrict__ Wv,
    const float* __restrict__ Aq,
    const float* __restrict__ Ak,
    const float* __restrict__ Av,
    unsigned short* __restrict__ ws)
{
  const int sblk = blockIdx.x;
  const int nblk = blockIdx.y;
  const int z = blockIdx.z;
  const int b = z / 3, p = z % 3;
  const float* W  = (p == 0) ? Wq : ((p == 1) ? Wk : Wv);
  const float* Ap = (p == 0) ? Aq : ((p == 1) ? Ak : Av);
  const float sig = 1.0f / (1.0f + __expf(-Ap[0]));

  __shared__ __align__(16) unsigned short As[64][40];
  __shared__ __align__(16) unsigned short Bs[64][40];

  const int tid = threadIdx.x;
  const int w = tid >> 6, lane = tid & 63;
  const int l15 = lane & 15, quad = lane >> 4;

  floatx4 acc[4];
#pragma unroll
  for (int i = 0; i < 4; ++i) acc[i] = (floatx4){0.f, 0.f, 0.f, 0.f};

  for (int cc = 0; cc < 16; ++cc) {
    const int c0 = cc * 32;
    __syncthreads();
#pragma unroll
    for (int t = 0; t < 2; ++t) {
      const int i = tid * 2 + t;
      const int c = i >> 4, sq = i & 15;
      const floatx4 g = *(const floatx4*)(inp + ((size_t)(b * C_INN + c0 + c) * SEQL + sblk * 64 + sq * 4));
      As[sq * 4 + 0][c] = f2bf(g[0]); As[sq * 4 + 1][c] = f2bf(g[1]);
      As[sq * 4 + 2][c] = f2bf(g[2]); As[sq * 4 + 3][c] = f2bf(g[3]);
    }
#pragma unroll
    for (int t = 0; t < 2; ++t) {
      const int i = tid * 2 + t;
      const int c = i >> 4, nq = i & 15;
      const floatx4 g = *(const floatx4*)(W + ((size_t)(c0 + c) * 1024 + nblk * 64 + nq * 4));
      Bs[nq * 4 + 0][c] = f2bf(g[0]); Bs[nq * 4 + 1][c] = f2bf(g[1]);
      Bs[nq * 4 + 2][c] = f2bf(g[2]); Bs[nq * 4 + 3][c] = f2bf(g[3]);
    }
    __syncthreads();
    const short8 a = *(const short8*)&As[w * 16 + l15][quad * 8];
#pragma unroll
    for (int nt = 0; nt < 4; ++nt) {
      const short8 bb = *(const short8*)&Bs[nt * 16 + l15][quad * 8];
      acc[nt] = __builtin_amdgcn_mfma_f32_16x16x32_bf16(a, bb, acc[nt], 0, 0, 0);
    }
  }

  unsigned short* out = ws + (size_t)p * ((size_t)B_S * N_H * SEQL * D_K);
#pragma unroll
  for (int nt = 0; nt < 4; ++nt) {
    const int h = l15;
    const int d = nblk * 4 + nt;
#pragma unroll
    for (int r = 0; r < 4; ++r) {
      const int s = sblk * 64 + w * 16 + quad * 4 + r;
      const float vout = acc[nt][r] * sig;
      if (p == 2) out[((size_t)((b * N_H + h) * D_K + d)) * SEQL + s] = f2bf(vout);
      else        out[((size_t)((b * N_H + h) * SEQL + s)) * D_K + d] = f2bf(vout);
    }
  }
}

// ---------------------------------------------------------------------------
// K2a: partial l. grid(64 qblk, KSL, 2 b); wave w handles 16-k tile ks*64+w*16
// independently. J^T in registers (2 head-groups of 8 to bound pressure).
// ---------------------------------------------------------------------------
__global__ __launch_bounds__(256, 4) void ath_lpart(
    const float* __restrict__ maskp,
    const float* __restrict__ Wl,
    const unsigned short* __restrict__ qkv,
    float* __restrict__ lp)
{
  const int qblk = blockIdx.x;
  const int ks   = blockIdx.y;
  const int b    = blockIdx.z;
  const int tid = threadIdx.x;
  const int w = tid >> 6, lane = tid & 63;
  const int l15 = lane & 15, quad = lane >> 4;

  const unsigned short* Qf = qkv;
  const unsigned short* Kf = qkv + (size_t)B_S * N_H * SEQL * D_K;

  const int kabs0 = ks * 64 + w * 16;

  float mk[4];
#pragma unroll
  for (int r = 0; r < 4; ++r) mk[r] = maskp[b * SEQL + kabs0 + quad * 4 + r];

  floatx4 el[16];
#pragma unroll
  for (int g = 0; g < 16; ++g) el[g] = (floatx4){-mk[0], -mk[1], -mk[2], -mk[3]};

#pragma unroll
  for (int hg = 0; hg < 2; ++hg) {
    floatx4 jc8[8];
#pragma unroll
    for (int hh = 0; hh < 8; ++hh) {
      const int h = hg * 8 + hh;
      const unsigned short* qb = Qf + ((size_t)((b * N_H + h) * SEQL) + qblk * 16 + l15) * D_K;
      const unsigned short* kb = Kf + ((size_t)((b * N_H + h) * SEQL) + kabs0 + l15) * D_K;
      const short8 q0 = *(const short8*)(qb + quad * 8);
      const short8 q1 = *(const short8*)(qb + 32 + quad * 8);
      const short8 k0 = *(const short8*)(kb + quad * 8);
      const short8 k1 = *(const short8*)(kb + 32 + quad * 8);
      floatx4 c = (floatx4){0.f, 0.f, 0.f, 0.f};
      c = __builtin_amdgcn_mfma_f32_16x16x32_bf16(k0, q0, c, 0, 0, 0);  // A=K -> rows k
      c = __builtin_amdgcn_mfma_f32_16x16x32_bf16(k1, q1, c, 0, 0, 0);
      jc8[hh] = c;
    }
#pragma unroll
    for (int g = 0; g < 16; ++g) {
      floatx4 e = el[g];
#pragma unroll
      for (int hh = 0; hh < 8; ++hh) {
        const float wv = Wl[(hg * 8 + hh) * 16 + g];  // wave-uniform -> s_load
        e[0] += jc8[hh][0] * wv; e[1] += jc8[hh][1] * wv;
        e[2] += jc8[hh][2] * wv; e[3] += jc8[hh][3] * wv;
      }
      el[g] = e;
    }
  }

  float lac[16];
#pragma unroll
  for (int g = 0; g < 16; ++g) {
    lac[g] = __expf(fminf(fmaxf(el[g][0], -60.f), 60.f))
           + __expf(fminf(fmaxf(el[g][1], -60.f), 60.f))
           + __expf(fminf(fmaxf(el[g][2], -60.f), 60.f))
           + __expf(fminf(fmaxf(el[g][3], -60.f), 60.f));
  }

  // reduce across the 4 quads (same l15)
#pragma unroll
  for (int g = 0; g < 16; ++g) {
    float v = lac[g];
    v += __shfl_xor(v, 16);
    v += __shfl_xor(v, 32);
    lac[g] = v;
  }
  if (quad == 0) {
    const int kse = ks * 4 + w;
    float* dst = lp + ((size_t)((kse * 2 + b) * SEQL + qblk * 16 + l15)) * 16;
#pragma unroll
    for (int g4 = 0; g4 < 4; ++g4)
      *(floatx4*)(dst + g4 * 4) = (floatx4){lac[g4 * 4], lac[g4 * 4 + 1], lac[g4 * 4 + 2], lac[g4 * 4 + 3]};
  }
}

// ---------------------------------------------------------------------------
// K2r: invl = 1 / sum_{kse<64} lp. grid(128, 256 thr).
// ---------------------------------------------------------------------------
__global__ __launch_bounds__(256) void ath_linv(
    const float* __restrict__ lp, float* __restrict__ invl)
{
  const int t = blockIdx.x * 256 + threadIdx.x;
  const int b = t >> 14, rem = t & 16383;
  float s = 0.f;
  for (int kse = 0; kse < 64; ++kse) s += lp[(size_t)((kse * 2 + b)) * 16384 + rem];
  invl[t] = 1.0f / fmaxf(s, 1e-37f);
}

// ---------------------------------------------------------------------------
// K2b: partial O. grid(64 qblk, KSO, 2 b). kchunk=128 -> 2 rounds of 64 k
// (wave w owns 16-k tile w). Mix in registers with 2x8-head grouping (el[16]
// persistent), U -> padded LDS v-exchange, barrier, V-phase (bf16 K=32 MFMA).
// ---------------------------------------------------------------------------
__global__ __launch_bounds__(256, 2) void ath_opart(
    const float* __restrict__ maskp,
    const float* __restrict__ Wl,
    const float* __restrict__ Ww,
    const unsigned short* __restrict__ qkv,
    const float* __restrict__ invl,
    unsigned short* __restrict__ Obp)
{
  const int qblk = blockIdx.x;
  const int ks   = blockIdx.y;
  const int b    = blockIdx.z;
  const int tid = threadIdx.x;
  const int w = tid >> 6, lane = tid & 63;
  const int l15 = lane & 15, quad = lane >> 4;

  const unsigned short* Qf = qkv;
  const unsigned short* Kf = qkv + (size_t)B_S * N_H * SEQL * D_K;
  const unsigned short* Vf = qkv + 2 * (size_t)B_S * N_H * SEQL * D_K;

  // Us: b64 slots [tile4][v16][qw4][q16 +1pad] -> 4*16*4*17 * 8B = 34.8KB
  __shared__ __align__(16) unsigned int UsU[4 * 16 * 4 * 17 * 2];
  __shared__ float invls[16][16];
  uint2v* Us2 = (uint2v*)UsU;

  invls[tid >> 4][tid & 15] =
      invl[(size_t)b * 16384 + (qblk * 16 + (tid >> 4)) * 16 + (tid & 15)];

  floatx4 oacc[4][4];
#pragma unroll
  for (int a = 0; a < 4; ++a)
#pragma unroll
    for (int d = 0; d < 4; ++d) oacc[a][d] = (floatx4){0.f, 0.f, 0.f, 0.f};

  __syncthreads();  // invls visible

  for (int rd = 0; rd < 2; ++rd) {
    const int kabs0 = ks * 128 + rd * 64 + w * 16;

    float mk[4];
#pragma unroll
    for (int r = 0; r < 4; ++r) mk[r] = maskp[b * SEQL + kabs0 + quad * 4 + r];

    // ---- EL accumulator; fold head-groups of 8 as their J^T lands ----
    floatx4 el[16];
#pragma unroll
    for (int g = 0; g < 16; ++g) el[g] = (floatx4){-mk[0], -mk[1], -mk[2], -mk[3]};

#pragma unroll
    for (int hg = 0; hg < 2; ++hg) {
      floatx4 jc8[8];
#pragma unroll
      for (int hh = 0; hh < 8; ++hh) {
        const int h = hg * 8 + hh;
        const unsigned short* qb = Qf + ((size_t)((b * N_H + h) * SEQL) + qblk * 16 + l15) * D_K;
        const unsigned short* kb = Kf + ((size_t)((b * N_H + h) * SEQL) + kabs0 + l15) * D_K;
        const short8 q0 = *(const short8*)(qb + quad * 8);
        const short8 q1 = *(const short8*)(qb + 32 + quad * 8);
        const short8 k0 = *(const short8*)(kb + quad * 8);
        const short8 k1 = *(const short8*)(kb + 32 + quad * 8);
        floatx4 c = (floatx4){0.f, 0.f, 0.f, 0.f};
        c = __builtin_amdgcn_mfma_f32_16x16x32_bf16(k0, q0, c, 0, 0, 0);
        c = __builtin_amdgcn_mfma_f32_16x16x32_bf16(k1, q1, c, 0, 0, 0);
        jc8[hh] = c;
      }
#pragma unroll
      for (int g = 0; g < 16; ++g) {
        floatx4 e = el[g];
#pragma unroll
        for (int hh = 0; hh < 8; ++hh) {
          const float wv = Wl[(hg * 8 + hh) * 16 + g];  // wave-uniform -> s_load
          e[0] += jc8[hh][0] * wv; e[1] += jc8[hh][1] * wv;
          e[2] += jc8[hh][2] * wv; e[3] += jc8[hh][3] * wv;
        }
        el[g] = e;
      }
    }

    // ---- softmax scale in place: el := exp(clamp(el)) * invl ----
#pragma unroll
    for (int g = 0; g < 16; ++g) {
      const float iv = invls[l15][g];
      floatx4 e = el[g];
#pragma unroll
      for (int r = 0; r < 4; ++r)
        e[r] = __expf(fminf(fmaxf(e[r], -60.f), 60.f)) * iv;
      el[g] = e;
    }

    // ---- U mix (Ww scalar-uniform) -> Us exchange ----
#pragma unroll
    for (int v = 0; v < 16; ++v) {
      float u0 = 0.f, u1 = 0.f, u2 = 0.f, u3 = 0.f;
#pragma unroll
      for (int g = 0; g < 16; ++g) {
        const float wv = Ww[g * 16 + v];
        u0 += el[g][0] * wv; u1 += el[g][1] * wv;
        u2 += el[g][2] * wv; u3 += el[g][3] * wv;
      }
      Us2[((w * 16 + v) * 4 + quad) * 17 + l15] = (uint2v){pkbf(u0, u1), pkbf(u2, u3)};
    }

    __syncthreads();  // all waves' U ready

    // ---- V-phase: wave w -> v = 4w..4w+3, two K=32 MFMAs cover 64 k ----
#pragma unroll
    for (int tp = 0; tp < 2; ++tp) {
      const int t = tp * 2 + (quad >> 1);
      const int qwb = (quad & 1) * 2;
      const int kt_abs = ks * 128 + rd * 64 + tp * 32;
#pragma unroll
      for (int vv = 0; vv < 4; ++vv) {
        const int v = w * 4 + vv;
        const int i1 = ((t * 16 + v) * 4 + qwb) * 17 + l15;
        union { uint2v a[2]; short8 s; } ux;
        ux.a[0] = Us2[i1];
        ux.a[1] = Us2[i1 + 17];
#pragma unroll
        for (int dt = 0; dt < 4; ++dt) {
          const short8 vfr = *(const short8*)(Vf +
              ((size_t)((b * N_H + v) * D_K + dt * 16 + l15)) * SEQL + kt_abs + quad * 8);
          oacc[vv][dt] = __builtin_amdgcn_mfma_f32_16x16x32_bf16(ux.s, vfr, oacc[vv][dt], 0, 0, 0);
        }
      }
    }

    __syncthreads();  // Us free for next round
  }

  // write partial O bf16: Obp[ks][b][q][d*16+v]
#pragma unroll
  for (int vv = 0; vv < 4; ++vv) {
    const int v = w * 4 + vv;
#pragma unroll
    for (int dt = 0; dt < 4; ++dt) {
      const int d = dt * 16 + l15;
#pragma unroll
      for (int r = 0; r < 4; ++r) {
        const int q = qblk * 16 + quad * 4 + r;
        Obp[(size_t)ks * BQJ + ((size_t)(b * SEQL + q)) * 1024 + d * 16 + v] = f2bf(oacc[vv][dt][r]);
      }
    }
  }
}

// ---------------------------------------------------------------------------
// K2s: Obsum = sum_ks Obp. grid(1024, 256 thr).
// ---------------------------------------------------------------------------
__global__ __launch_bounds__(256) void ath_osum(
    const unsigned short* __restrict__ Obp,
    unsigned short* __restrict__ Obsum)
{
  const size_t i = ((size_t)blockIdx.x * 256 + threadIdx.x) * 8;
  float a[8];
#pragma unroll
  for (int e = 0; e < 8; ++e) a[e] = 0.f;
#pragma unroll
  for (int ks = 0; ks < KSO; ++ks) {
    const short8 v = *(const short8*)(Obp + (size_t)ks * BQJ + i);
#pragma unroll
    for (int e = 0; e < 8; ++e) a[e] += bf2f((unsigned short)v[e]);
  }
  short8 o;
#pragma unroll
  for (int e = 0; e < 8; ++e) o[e] = (short)f2bf(a[e]);
  *(short8*)(Obsum + i) = o;
}

// ---------------------------------------------------------------------------
// Kernel 3: out[b][co][q] = inp + sum_j Obsum[b][q][j] * Wo[j][co]. fp32 out.
// ---------------------------------------------------------------------------
__global__ __launch_bounds__(256) void ath_out(
    const float* __restrict__ inp,
    const float* __restrict__ Wo,
    const unsigned short* __restrict__ Ob,
    float* __restrict__ out)
{
  const int qblk = blockIdx.x;
  const int cblk = blockIdx.y;
  const int b    = blockIdx.z;
  const int tid = threadIdx.x;
  const int w = tid >> 6, lane = tid & 63;
  const int l15 = lane & 15, quad = lane >> 4;

  __shared__ __align__(16) unsigned short Os[64][40];
  __shared__ __align__(16) unsigned short Wt[64][40];

  floatx4 acc[4];
#pragma unroll
  for (int i = 0; i < 4; ++i) acc[i] = (floatx4){0.f, 0.f, 0.f, 0.f};

  for (int jc = 0; jc < 32; ++jc) {
    const int j0 = jc * 32;
    __syncthreads();
    {
      const int q = tid >> 2, jq = tid & 3;
      const unsigned short* g = Ob + ((size_t)(b * SEQL + qblk * 64 + q)) * 1024 + j0 + jq * 8;
      *(short8*)&Os[q][jq * 8] = *(const short8*)g;
    }
#pragma unroll
    for (int t = 0; t < 2; ++t) {
      const int i = tid * 2 + t;
      const int j = i >> 4, cq = i & 15;
      const floatx4 g = *(const floatx4*)(Wo + ((size_t)(j0 + j) * 512 + cblk * 64 + cq * 4));
      Wt[cq * 4 + 0][j] = f2bf(g[0]); Wt[cq * 4 + 1][j] = f2bf(g[1]);
      Wt[cq * 4 + 2][j] = f2bf(g[2]); Wt[cq * 4 + 3][j] = f2bf(g[3]);
    }
    __syncthreads();
    const short8 a = *(const short8*)&Os[w * 16 + l15][quad * 8];
#pragma unroll
    for (int nt = 0; nt < 4; ++nt) {
      const short8 bb = *(const short8*)&Wt[nt * 16 + l15][quad * 8];
      acc[nt] = __builtin_amdgcn_mfma_f32_16x16x32_bf16(a, bb, acc[nt], 0, 0, 0);
    }
  }

#pragma unroll
  for (int nt = 0; nt < 4; ++nt) {
    const int co = cblk * 64 + nt * 16 + l15;
    const int qb = qblk * 64 + w * 16 + quad * 4;
    const float* ip = inp + ((size_t)(b * 512 + co)) * SEQL + qb;
    float* op = out + ((size_t)(b * 512 + co)) * SEQL + qb;
#pragma unroll
    for (int r = 0; r < 4; ++r) op[r] = acc[nt][r] + ip[r];
  }
}

// ---------------------------------------------------------------------------
extern "C" void kernel_launch(void* const* d_in, const int* in_sizes, int n_in,
                              void* d_out, int out_size, void* d_ws, size_t ws_size,
                              hipStream_t stream) {
  (void)in_sizes; (void)n_in; (void)out_size; (void)ws_size;
  const float* inp   = (const float*)d_in[0];
  const float* maskp = (const float*)d_in[1];
  const float* Wq    = (const float*)d_in[2];
  const float* Wk    = (const float*)d_in[3];
  const float* Wv    = (const float*)d_in[4];
  const float* Aq    = (const float*)d_in[5];
  const float* Ak    = (const float*)d_in[6];
  const float* Av    = (const float*)d_in[7];
  const float* Wl    = (const float*)d_in[8];
  const float* Ww    = (const float*)d_in[9];
  const float* Wo    = (const float*)d_in[10];

  const size_t MB = 1u << 20;
  unsigned short* qkv   = (unsigned short*)d_ws;                       // 12 MB bf16 Q,K,V
  unsigned short* Obsum = (unsigned short*)((char*)d_ws + 12 * MB);    // 4 MB bf16
  float*          invl  = (float*)((char*)d_ws + 16 * MB);             // 128 KB
  float*          lp    = (float*)((char*)d_ws + 18 * MB);             // 8 MB (dead before Obp use)
  unsigned short* Obp   = (unsigned short*)((char*)d_ws + 18 * MB);    // KSO*4 MB = 32 MB
  float* out = (float*)d_out;

  ath_qkv<<<dim3(16, 16, 6), 256, 0, stream>>>(inp, Wq, Wk, Wv, Aq, Ak, Av, qkv);
  ath_lpart<<<dim3(64, KSL, 2), 256, 0, stream>>>(maskp, Wl, qkv, lp);
  ath_linv<<<dim3(128), 256, 0, stream>>>(lp, invl);
  ath_opart<<<dim3(64, KSO, 2), 256, 0, stream>>>(maskp, Wl, Ww, qkv, invl, Obp);
  ath_osum<<<dim3(1024), 256, 0, stream>>>(Obp, Obsum);
  ath_out<<<dim3(16, 8, 2), 256, 0, stream>>>(inp, Wo, Obsum, out);
}